// Round 5
// baseline (2001.773 us; speedup 1.0000x reference)
//
// ODE-RNN (B=128, F=512, I=128, H=512, O=1) on MI355X — Round 17.
// R16 = 1.56 ms = 512 x ~6900 cy. The loop is a LOCKSTEP: every block runs
// C -> signal -> D -> wait -> post serially, so the frame period is the
// serial SUM (D's 36 MFMA + 16 loads sit in every frame though nothing in D
// gates the next publish). R17 splits the lockstep: 512-thread blocks,
// 4 CRITICAL waves run only the gating chain
//   poll(hflag,gflag) -> ld16 h_{f-1} -> u=Whh*h (16 MFMA) -> read LDS
//   {vpre,accx,dsc} -> tanh -> publish h_f -> drain -> cbar -> hflag
// and 4 HELPER waves run everything else one frame ahead:
//   poll -> ld16 h_v -> z=W1*h_v -> publish g1_v to 4-deep L2 ring (own
//   gflag) -> ld16 g1_{v-1} -> vpre=Whh2*g1 -> accx=Wih*x_{v+2} -> LDS
//   mailbox for crit frame v+2 (seq release/acquire).
// No __syncthreads in the loop (LDS counters instead). g-staleness back to
// 2 frames (R15-proven accuracy). h/g rings 4-deep; overwrite safety closed
// by sequential per-block execution + hflag/gflag attestation (see polls).
// vb = Whh2*relu(b1) precomputed host-side seeds frame-1 vpre.
// Predicted: 600-1000 us; MfmaUtil 5-8, VGPR ~240, 8 waves/CU.

#include <hip/hip_runtime.h>
#include <hip/hip_bf16.h>
#include <cstdint>
#include <cstddef>

#define HD 512
#define ID 128
#define FF 512
#define G 4          // groups (each owns 32 samples)
#define S 32         // samples per group
#define NBLK 16      // blocks per group (32-col weight shards)
#define NLAUNCH 256  // blocks launched (>= 9 complete cohorts by pigeonhole)

// ctl word offsets (all zeroed before seq_kernel)
#define CT_TICKET 0          // [16] per-XCD ticket counters
#define CT_CLAIM 16          // group claim counter
#define CT_TOTAL 17          // registered-block counter
#define CT_MAP 20            // [256] cohort -> group+1 (0 = unclaimed)
#define CT_FSTRIDE 32        // words between flags (128B: own L2 line)
#define CT_PFLAG 512                                   // h flags [G][16*32]
#define CT_GFLAG (CT_PFLAG + G * NBLK * CT_FSTRIDE)    // g flags [G][16*32]
#define CT_WORDS (CT_GFLAG + G * NBLK * CT_FSTRIDE)

#define XFRAG_ELEMS ((size_t)FF * 8 * 4 * 64 * 8)   // 8,388,608 bf16

// per-group activation region: [h ring 0..3][g ring 0..3] x S*512 bf16
#define ACT_PER_GROUP ((size_t)8 * S * 512)

typedef __bf16 bf16x8_t __attribute__((ext_vector_type(8)));
typedef unsigned short ushort8_t __attribute__((ext_vector_type(8)));
typedef unsigned short ushort4_t __attribute__((ext_vector_type(4)));
typedef float f32x4_t __attribute__((ext_vector_type(4)));

__device__ __forceinline__ unsigned short f2b(float x) {
  __hip_bfloat16 h = __float2bfloat16(x);
  return *reinterpret_cast<unsigned short*>(&h);
}
__device__ __forceinline__ bf16x8_t ld_frag(const unsigned short* p) {
  ushort8_t u = *reinterpret_cast<const ushort8_t*>(p);
  return __builtin_bit_cast(bf16x8_t, u);
}

// --- fp32 -> bf16 fragment-order weight pack (same layout as R3-R16) -------
__global__ void pack_kernel(const float* __restrict__ in,
                            unsigned short* __restrict__ out, int Kd) {
  int i = blockIdx.x * blockDim.x + threadIdx.x;
  int total = HD * Kd;
  if (i >= total) return;
  int KT = Kd >> 5;
  int j = i & 7;
  int lane = (i >> 3) & 63;
  int t = i >> 9;
  int kt = t % KT;
  int colt = t / KT;
  int n = lane & 15, kq = lane >> 4;
  out[i] = f2b(in[(size_t)(colt * 16 + n) * Kd + kt * 32 + kq * 8 + j]);
}

// --- C = A * B (512x512 fp32 row-major), naive-but-adequate (~tens of us) --
__global__ void mm512_kernel(const float* __restrict__ A,
                             const float* __restrict__ B,
                             float* __restrict__ C) {
  const int i = blockIdx.x;          // row
  const int j0 = threadIdx.x;        // col (and col+256)
  float acc0 = 0.f, acc1 = 0.f;
#pragma unroll 8
  for (int k = 0; k < 512; ++k) {
    float a = A[i * 512 + k];
    acc0 += a * B[k * 512 + j0];
    acc1 += a * B[k * 512 + j0 + 256];
  }
  C[i * 512 + j0] = acc0;
  C[i * 512 + j0 + 256] = acc1;
}

// --- out = W (512x512) * v (512) ------------------------------------------
__global__ void mv_kernel(const float* __restrict__ W,
                          const float* __restrict__ v,
                          float* __restrict__ out) {
  int i = blockIdx.x * blockDim.x + threadIdx.x;
  if (i >= 512) return;
  float s = 0.f;
#pragma unroll 8
  for (int k = 0; k < 512; ++k) s += W[(size_t)i * 512 + k] * v[k];
  out[i] = s;
}

// --- out = W (512x512) * relu(v) ------------------------------------------
__global__ void mv_relu_kernel(const float* __restrict__ W,
                               const float* __restrict__ v,
                               float* __restrict__ out) {
  int i = blockIdx.x * blockDim.x + threadIdx.x;
  if (i >= 512) return;
  float s = 0.f;
#pragma unroll 8
  for (int k = 0; k < 512; ++k) {
    float g = v[k] > 0.f ? v[k] : 0.f;
    s += W[(size_t)i * 512 + k] * g;
  }
  out[i] = s;
}

// --- x -> bf16 B-fragment order: xf[f][st=b>>4][kt<4][lane=n+16kq][8] ------
__global__ void xpack_kernel(const float* __restrict__ in,
                             unsigned short* __restrict__ out) {
  size_t i = (size_t)blockIdx.x * blockDim.x + threadIdx.x;
  if (i >= XFRAG_ELEMS) return;
  int e = (int)(i & 7);
  int lane = (int)((i >> 3) & 63);
  int kt = (int)((i >> 9) & 3);
  int st = (int)((i >> 11) & 7);
  int f = (int)(i >> 14);
  int n = lane & 15, kq = lane >> 4;
  int b = st * 16 + n;
  int ii = kt * 32 + kq * 8 + e;
  out[i] = f2b(in[((size_t)b * FF + f) * ID + ii]);
}

// --- dt table: dtp[f*128 + b] = tp[b][f] - tp[b][f-1] (0 at f=0) -----------
__global__ void dtpack_kernel(const float* __restrict__ tp,
                              float* __restrict__ dtp) {
  int i = blockIdx.x * blockDim.x + threadIdx.x;
  if (i >= FF * 128) return;
  int f = i >> 7, b = i & 127;
  dtp[i] = (f > 0) ? (tp[(size_t)b * FF + f] - tp[(size_t)b * FF + f - 1])
                   : 0.f;
}

__global__ void zero_kernel(unsigned int* __restrict__ p, int n) {
  int i = blockIdx.x * blockDim.x + threadIdx.x;
  if (i < n) p[i] = 0u;
}

// Load the 16 activation frags of this wave's K-slab into registers.
__device__ __forceinline__ void ld16(const ushort8_t* base, int row0,
                                     int lane, bf16x8_t a[16]) {
#pragma unroll
  for (int kt = 0; kt < 16; ++kt)
    a[kt] = __builtin_bit_cast(bf16x8_t, base[(row0 + kt) * 64 + lane]);
}
// acc += W-shard @ act, two interleaved 8-chains (helper-path version).
__device__ __forceinline__ f32x4_t mm16r(const bf16x8_t* wf,
                                         const bf16x8_t a[16], f32x4_t acc) {
  f32x4_t acc1 = {0.f, 0.f, 0.f, 0.f};
#pragma unroll
  for (int kt = 0; kt < 16; kt += 2) {
    acc  = __builtin_amdgcn_mfma_f32_16x16x32_bf16(wf[kt], a[kt], acc, 0, 0, 0);
    acc1 = __builtin_amdgcn_mfma_f32_16x16x32_bf16(wf[kt + 1], a[kt + 1], acc1,
                                                   0, 0, 0);
  }
  acc[0] += acc1[0]; acc[1] += acc1[1]; acc[2] += acc1[2]; acc[3] += acc1[3];
  return acc;
}
// Critical-path version: 4 interleaved chains x 4-deep (halved latency).
__device__ __forceinline__ f32x4_t mm16r44(const bf16x8_t* wf,
                                           const bf16x8_t a[16]) {
  f32x4_t c0 = {0.f, 0.f, 0.f, 0.f}, c1 = {0.f, 0.f, 0.f, 0.f};
  f32x4_t c2 = {0.f, 0.f, 0.f, 0.f}, c3 = {0.f, 0.f, 0.f, 0.f};
#pragma unroll
  for (int i = 0; i < 4; ++i) {
    c0 = __builtin_amdgcn_mfma_f32_16x16x32_bf16(wf[i * 4 + 0], a[i * 4 + 0],
                                                 c0, 0, 0, 0);
    c1 = __builtin_amdgcn_mfma_f32_16x16x32_bf16(wf[i * 4 + 1], a[i * 4 + 1],
                                                 c1, 0, 0, 0);
    c2 = __builtin_amdgcn_mfma_f32_16x16x32_bf16(wf[i * 4 + 2], a[i * 4 + 2],
                                                 c2, 0, 0, 0);
    c3 = __builtin_amdgcn_mfma_f32_16x16x32_bf16(wf[i * 4 + 3], a[i * 4 + 3],
                                                 c3, 0, 0, 0);
  }
#pragma unroll
  for (int r_ = 0; r_ < 4; ++r_) c0[r_] = (c0[r_] + c1[r_]) + (c2[r_] + c3[r_]);
  return c0;
}
// fast tanh: clamp + __expf + rcp, |err| ~ 1e-6, no libm call.
__device__ __forceinline__ float ftanh(float x) {
  float xc = fminf(fmaxf(x, -15.f), 15.f);
  float e = __expf(2.f * xc);
  return (e - 1.f) * __builtin_amdgcn_rcpf(e + 1.f);
}

// --- the sequential recurrence ---------------------------------------------
__global__ __launch_bounds__(512, 1) void seq_kernel(
    const float* __restrict__ dtp,
    const float* __restrict__ b1, const float* __restrict__ cw,
    const float* __restrict__ vb,
    const float* __restrict__ bih, const float* __restrict__ bhh,
    const float* __restrict__ Wc,
    const unsigned short* __restrict__ W1p,
    const unsigned short* __restrict__ Whhp,
    const unsigned short* __restrict__ Whh2p,
    const unsigned short* __restrict__ Wihp,
    const unsigned short* __restrict__ xf,
    unsigned short* __restrict__ actg,   // G * ACT_PER_GROUP bf16
    unsigned int* __restrict__ ctl,      // control words (see CT_*)
    float* __restrict__ logits) {        // 128 fp32, pre-zeroed
  __shared__ float redl[S][2];
  __shared__ int role[2];
  __shared__ unsigned seqw[2][4];       // [slot][crit-wave] mailbox seq
  __shared__ int cbar, gbar;            // role-local barriers (monotone)
  __shared__ float mb[2][4][64 * 12];   // [slot][wave][lane*12]: vpre4,accx4,dsc

  const int tid = threadIdx.x;
  if (tid < 8) ((unsigned*)seqw)[tid] = 0u;
  if (tid == 8) { cbar = 0; gbar = 0; }

  // ---- XCD-aware registration & group claiming (tid 0; R5-R16 proven) -----
  if (tid == 0) {
    unsigned xcc;
    asm volatile("s_getreg_b32 %0, hwreg(HW_REG_XCC_ID, 0, 32)" : "=s"(xcc));
    const int xcd = (int)(xcc & 15u);
    unsigned rank = __hip_atomic_fetch_add(&ctl[CT_TICKET + xcd], 1u,
                                           __ATOMIC_RELAXED,
                                           __HIP_MEMORY_SCOPE_AGENT);
    const unsigned slot = (unsigned)xcd * 16u + (rank >> 4);
    if ((rank & 15u) == 15u) {  // cohort completer claims a group id
      unsigned gg = __hip_atomic_fetch_add(&ctl[CT_CLAIM], 1u,
                                           __ATOMIC_RELAXED,
                                           __HIP_MEMORY_SCOPE_AGENT);
      __hip_atomic_store(&ctl[CT_MAP + slot], gg + 1u, __ATOMIC_RELAXED,
                         __HIP_MEMORY_SCOPE_AGENT);
      asm volatile("s_waitcnt vmcnt(0)" ::: "memory");  // publish before total
    }
    __hip_atomic_fetch_add(&ctl[CT_TOTAL], 1u, __ATOMIC_RELAXED,
                           __HIP_MEMORY_SCOPE_AGENT);
    unsigned m;
    for (;;) {
      m = __hip_atomic_load(&ctl[CT_MAP + slot], __ATOMIC_RELAXED,
                            __HIP_MEMORY_SCOPE_AGENT);
      if (m) break;
      if (__hip_atomic_load(&ctl[CT_TOTAL], __ATOMIC_RELAXED,
                            __HIP_MEMORY_SCOPE_AGENT) >= (unsigned)NLAUNCH) {
        m = __hip_atomic_load(&ctl[CT_MAP + slot], __ATOMIC_RELAXED,
                              __HIP_MEMORY_SCOPE_AGENT);
        break;
      }
      __builtin_amdgcn_s_sleep(2);
    }
    role[0] = (m == 0 || m > (unsigned)G) ? -1 : (int)(m - 1);
    role[1] = (int)(rank & 15u);
  }
  __syncthreads();
  if (role[0] < 0) return;   // surplus / incomplete cohort: exit
  const int g = role[0];     // group id 0..3  (samples [g*32, g*32+32))
  const int j = role[1];     // 32-col weight shard 0..15

  const int wave = tid >> 6;
  const int lane = tid & 63;
  const int n = lane & 15;
  const int kq = lane >> 4;
  const int w2 = wave & 3;         // tile index within role
  const int ct = w2 & 1;           // col-tile within shard
  const int rt = w2 >> 1;          // row-tile (samples)
  const int colt = j * 2 + ct;     // global 16-col tile
  const int sl2 = rt * 16 + n;     // this lane's sample (D col = lane&15)
  const int gc0 = j * 32 + ct * 16 + kq * 4;  // lane's 4-col base (D rows)
  const int s0 = g * S;

  unsigned short* const myact = actg + (size_t)g * ACT_PER_GROUP;
  unsigned int* const hf = &ctl[CT_PFLAG + g * NBLK * CT_FSTRIDE];
  unsigned int* const gf = &ctl[CT_GFLAG + g * NBLK * CT_FSTRIDE];

  // Producer store offset (elems) in consumer B-frag order (R9-proven).
  const size_t soff =
      ((size_t)(rt * 16 + j) * 64 + n + 16 * (2 * ct + (kq >> 1))) * 8 +
      (kq & 1) * 4;
  const int row0 = rt * 16;

  asm volatile("buffer_inv" ::: "memory");   // drop any pre-kernel L1 lines
  asm volatile("s_waitcnt vmcnt(0)" ::: "memory");

  // combined flag poll: lanes 0-15 check hflag>=wh, lanes 16-31 gflag>=wg.
  auto poll2 = [&](unsigned wh, unsigned wg) {
    const bool gl = (lane >= 16 && lane < 32);
    const unsigned want = gl ? wg : wh;
    volatile const unsigned* fb =
        gl ? (volatile const unsigned*)gf : (volatile const unsigned*)hf;
    const int fi = gl ? (lane - 16) : (lane & 15);
    for (;;) {
      asm volatile("buffer_inv" ::: "memory");
      unsigned vv = fb[fi * CT_FSTRIDE];
      if (__ballot(vv < want) == 0ull) break;
    }
  };

  if (wave < 4) {
    // ================= CRITICAL waves: the gating chain =================
    bf16x8_t whhf[16];
#pragma unroll
    for (int kt = 0; kt < 16; ++kt)
      whhf[kt] = ld_frag(Whhp + (size_t)(colt * 16 + kt) * 512 + lane * 8);
    const f32x4_t cwv4 = *reinterpret_cast<const f32x4_t*>(&cw[gc0]);
    f32x4_t bbv;
#pragma unroll
    for (int r_ = 0; r_ < 4; ++r_) bbv[r_] = bih[gc0 + r_] + bhh[gc0 + r_];
    f32x4_t fsv = {0.f, 0.f, 0.f, 0.f};

#pragma unroll 1
    for (int f = 0; f < FF; ++f) {
      poll2((unsigned)f, f >= 2 ? (unsigned)(f - 2) : 0u);
      bf16x8_t ah[16];
      ld16((const ushort8_t*)(myact + (size_t)((f + 3) & 3) * (S * 512)),
           row0, lane, ah);
      f32x4_t u = mm16r44(whhf, ah);
      // mailbox for frame f (helper wrote slot f&1 with seq f+1)
      while (__hip_atomic_load(&seqw[f & 1][w2], __ATOMIC_ACQUIRE,
                               __HIP_MEMORY_SCOPE_WORKGROUP) <
             (unsigned)(f + 1)) {}
      const float* mbp = &mb[f & 1][w2][lane * 12];
      const f32x4_t vpre = *reinterpret_cast<const f32x4_t*>(mbp);
      const f32x4_t accx = *reinterpret_cast<const f32x4_t*>(mbp + 4);
      const float dsc = mbp[8];
      unsigned short* dsth = myact + (size_t)(f & 3) * (S * 512);
      ushort4_t oh;
#pragma unroll
      for (int r_ = 0; r_ < 4; ++r_) {
        float pre = accx[r_] + u[r_] + dsc * (vpre[r_] + cwv4[r_]) + bbv[r_];
        float t = ftanh(pre);
        fsv[r_] += t;
        oh[r_] = f2b(t);
      }
      *reinterpret_cast<ushort4_t*>(dsth + soff) = oh;
      asm volatile("s_waitcnt vmcnt(0)" ::: "memory");
      if (lane == 0)
        __hip_atomic_fetch_add(&cbar, 1, __ATOMIC_RELEASE,
                               __HIP_MEMORY_SCOPE_WORKGROUP);
      if (wave == 0 && lane == 0) {
        while (__hip_atomic_load(&cbar, __ATOMIC_ACQUIRE,
                                 __HIP_MEMORY_SCOPE_WORKGROUP) < 4 * (f + 1)) {}
        *(volatile unsigned int*)(hf + j * CT_FSTRIDE) = (unsigned)(f + 1);
      }
    }

    // classifier partial
    {
      float p = fsv[0] * Wc[gc0] + fsv[1] * Wc[gc0 + 1] +
                fsv[2] * Wc[gc0 + 2] + fsv[3] * Wc[gc0 + 3];
      p += __shfl_xor(p, 16, 64);
      p += __shfl_xor(p, 32, 64);
      if (lane < 16) redl[rt * 16 + lane][ct] = p;
    }
  } else {
    // ================= HELPER waves: everything else, 1 frame ahead ======
    bf16x8_t w1f[16], whh2f[16], wihf[4];
#pragma unroll
    for (int kt = 0; kt < 16; ++kt) {
      w1f[kt]   = ld_frag(W1p   + (size_t)(colt * 16 + kt) * 512 + lane * 8);
      whh2f[kt] = ld_frag(Whh2p + (size_t)(colt * 16 + kt) * 512 + lane * 8);
    }
#pragma unroll
    for (int kt = 0; kt < 4; ++kt)
      wihf[kt] = ld_frag(Wihp + (size_t)(colt * 4 + kt) * 512 + lane * 8);
    const f32x4_t b1v = *reinterpret_cast<const f32x4_t*>(&b1[gc0]);

    // ---- prologue: mailbox slots for frames 0 and 1; g1_{-1} to ring ----
    {
      // frame 0: vpre=0 (dt_0=0), accx = Wih*x_0, dsc = 0
      f32x4_t a0 = {0.f, 0.f, 0.f, 0.f};
      {
        const ushort8_t* xsrc =
            (const ushort8_t*)xf + (size_t)((0 * 8 + g * 2 + rt) * 4) * 64;
#pragma unroll
        for (int kt = 0; kt < 4; ++kt) {
          bf16x8_t a = __builtin_bit_cast(bf16x8_t, xsrc[kt * 64 + lane]);
          a0 = __builtin_amdgcn_mfma_f32_16x16x32_bf16(wihf[kt], a, a0, 0, 0, 0);
        }
      }
      float* mbp = &mb[0][w2][lane * 12];
      *reinterpret_cast<f32x4_t*>(mbp) = (f32x4_t){0.f, 0.f, 0.f, 0.f};
      *reinterpret_cast<f32x4_t*>(mbp + 4) = a0;
      mbp[8] = dtp[0 * 128 + s0 + sl2];
      __hip_atomic_store(&seqw[0][w2], 1u, __ATOMIC_RELEASE,
                         __HIP_MEMORY_SCOPE_WORKGROUP);
      // frame 1: vpre = vb frag (Whh2*relu(b1)), accx = Wih*x_1, dsc = dt_1
      f32x4_t a1 = {0.f, 0.f, 0.f, 0.f};
      {
        const ushort8_t* xsrc =
            (const ushort8_t*)xf + (size_t)((1 * 8 + g * 2 + rt) * 4) * 64;
#pragma unroll
        for (int kt = 0; kt < 4; ++kt) {
          bf16x8_t a = __builtin_bit_cast(bf16x8_t, xsrc[kt * 64 + lane]);
          a1 = __builtin_amdgcn_mfma_f32_16x16x32_bf16(wihf[kt], a, a1, 0, 0, 0);
        }
      }
      f32x4_t v1;
#pragma unroll
      for (int r_ = 0; r_ < 4; ++r_) v1[r_] = vb[gc0 + r_];
      mbp = &mb[1][w2][lane * 12];
      *reinterpret_cast<f32x4_t*>(mbp) = v1;
      *reinterpret_cast<f32x4_t*>(mbp + 4) = a1;
      mbp[8] = dtp[1 * 128 + s0 + sl2];
      __hip_atomic_store(&seqw[1][w2], 2u, __ATOMIC_RELEASE,
                         __HIP_MEMORY_SCOPE_WORKGROUP);
      // g1_{-1} = relu(b1) fragment -> g ring slot 3
      ushort4_t og;
#pragma unroll
      for (int r_ = 0; r_ < 4; ++r_)
        og[r_] = f2b(b1v[r_] > 0.f ? b1v[r_] : 0.f);
      *reinterpret_cast<ushort4_t*>(
          myact + (size_t)(4 + 3) * (S * 512) + soff) = og;
      asm volatile("s_waitcnt vmcnt(0)" ::: "memory");
      if (lane == 0)
        __hip_atomic_fetch_add(&gbar, 1, __ATOMIC_RELEASE,
                               __HIP_MEMORY_SCOPE_WORKGROUP);
      if (wave == 4 && lane == 0) {
        while (__hip_atomic_load(&gbar, __ATOMIC_ACQUIRE,
                                 __HIP_MEMORY_SCOPE_WORKGROUP) < 4) {}
        *(volatile unsigned int*)(gf + j * CT_FSTRIDE) = 1u;
      }
    }

#pragma unroll 1
    for (int v = 0; v <= FF - 3; ++v) {
      poll2((unsigned)(v + 1), (unsigned)(v + 1));
      const float dscn = dtp[(v + 2) * 128 + s0 + sl2];
      bf16x8_t ah[16];
      ld16((const ushort8_t*)(myact + (size_t)(v & 3) * (S * 512)),
           row0, lane, ah);                       // h_v
      bf16x8_t axf[4];
      {
        const ushort8_t* xsrc =
            (const ushort8_t*)xf +
            (size_t)(((v + 2) * 8 + g * 2 + rt) * 4) * 64;
#pragma unroll
        for (int kt = 0; kt < 4; ++kt)
          axf[kt] = __builtin_bit_cast(bf16x8_t, xsrc[kt * 64 + lane]);
      }
      // z = W1 * h_v -> publish g1_v
      f32x4_t z = {0.f, 0.f, 0.f, 0.f};
      z = mm16r(w1f, ah, z);
      ushort4_t og;
#pragma unroll
      for (int r_ = 0; r_ < 4; ++r_) {
        float zz = z[r_] + b1v[r_];
        og[r_] = f2b(zz > 0.f ? zz : 0.f);
      }
      *reinterpret_cast<ushort4_t*>(
          myact + (size_t)(4 + (v & 3)) * (S * 512) + soff) = og;
      asm volatile("s_waitcnt vmcnt(0)" ::: "memory");
      if (lane == 0)
        __hip_atomic_fetch_add(&gbar, 1, __ATOMIC_RELEASE,
                               __HIP_MEMORY_SCOPE_WORKGROUP);
      if (wave == 4 && lane == 0) {
        while (__hip_atomic_load(&gbar, __ATOMIC_ACQUIRE,
                                 __HIP_MEMORY_SCOPE_WORKGROUP) <
               4 * (v + 2)) {}
        *(volatile unsigned int*)(gf + j * CT_FSTRIDE) = (unsigned)(v + 2);
      }
      // vpre = Whh2 * g1_{v-1}  (attested by top poll gflag >= v+1)
      bf16x8_t ag[16];
      ld16((const ushort8_t*)(myact + (size_t)(4 + ((v + 3) & 3)) * (S * 512)),
           row0, lane, ag);
      f32x4_t vp = {0.f, 0.f, 0.f, 0.f};
      vp = mm16r(whh2f, ag, vp);
      // accx = Wih * x_{v+2}
      f32x4_t ax = {0.f, 0.f, 0.f, 0.f};
#pragma unroll
      for (int kt = 0; kt < 4; ++kt)
        ax = __builtin_amdgcn_mfma_f32_16x16x32_bf16(wihf[kt], axf[kt], ax,
                                                     0, 0, 0);
      // mailbox for frame v+2 (slot (v+2)&1 == v&1); own crit's read of this
      // slot (frame v) is attested by the top poll (hflag >= v+1).
      float* mbp = &mb[v & 1][w2][lane * 12];
      *reinterpret_cast<f32x4_t*>(mbp) = vp;
      *reinterpret_cast<f32x4_t*>(mbp + 4) = ax;
      mbp[8] = dscn;
      __hip_atomic_store(&seqw[v & 1][w2], (unsigned)(v + 3), __ATOMIC_RELEASE,
                         __HIP_MEMORY_SCOPE_WORKGROUP);
    }
  }

  __syncthreads();
  if (tid < S) {
    float v = redl[tid][0] + redl[tid][1];
    atomicAdd(&logits[s0 + tid], v);   // device-scope, cross-XCD safe
  }
}

__global__ void fin_kernel(const float* __restrict__ logits,
                           const float* __restrict__ bc,
                           float* __restrict__ out) {
  int b = threadIdx.x;
  if (b < 128) out[b] = 1.f / (1.f + __expf(-(logits[b] * (1.f / FF) + bc[0])));
}

// --- launch -----------------------------------------------------------------
extern "C" void kernel_launch(void* const* d_in, const int* in_sizes, int n_in,
                              void* d_out, int out_size, void* d_ws, size_t ws_size,
                              hipStream_t stream) {
  const float* x   = (const float*)d_in[0];
  const float* tp  = (const float*)d_in[1];
  const float* W1  = (const float*)d_in[2];
  const float* b1  = (const float*)d_in[3];
  const float* W2  = (const float*)d_in[4];
  const float* b2  = (const float*)d_in[5];
  const float* Wih = (const float*)d_in[6];
  const float* Whh = (const float*)d_in[7];
  const float* bih = (const float*)d_in[8];
  const float* bhh = (const float*)d_in[9];
  const float* Wc  = (const float*)d_in[10];
  const float* bc  = (const float*)d_in[11];
  float* out = (float*)d_out;

  unsigned short* W1p   = (unsigned short*)d_ws;
  unsigned short* Whhp  = W1p + (size_t)HD * HD;
  unsigned short* Whh2p = Whhp + (size_t)HD * HD;
  unsigned short* Wihp  = Whh2p + (size_t)HD * HD;
  unsigned short* xfp   = Wihp + (size_t)HD * ID;
  float*          dtp   = (float*)(xfp + XFRAG_ELEMS);
  float*          cwv   = dtp + FF * 128;
  float*          vbv   = cwv + HD;
  float*          Whh2t = vbv + HD;                 // fp32 temp 1MB
  unsigned short* actg  = (unsigned short*)(Whh2t + (size_t)HD * HD);
  unsigned int*   ctl   = (unsigned int*)(actg + (size_t)G * ACT_PER_GROUP);
  float*          logits = (float*)(ctl + CT_WORDS);
  // total ws use ~21 MB

  // precompute Whh2 = Whh*W2, cw = Whh*b2, vb = Whh2*relu(b1)
  mm512_kernel<<<512, 256, 0, stream>>>(Whh, W2, Whh2t);
  mv_kernel<<<2, 256, 0, stream>>>(Whh, b2, cwv);
  mv_relu_kernel<<<2, 256, 0, stream>>>(Whh2t, b1, vbv);

  pack_kernel<<<(HD * HD + 255) / 256, 256, 0, stream>>>(W1, W1p, HD);
  pack_kernel<<<(HD * HD + 255) / 256, 256, 0, stream>>>(Whh, Whhp, HD);
  pack_kernel<<<(HD * HD + 255) / 256, 256, 0, stream>>>(Whh2t, Whh2p, HD);
  pack_kernel<<<(HD * ID + 255) / 256, 256, 0, stream>>>(Wih, Wihp, ID);
  xpack_kernel<<<(int)((XFRAG_ELEMS + 255) / 256), 256, 0, stream>>>(x, xfp);
  dtpack_kernel<<<(FF * 128 + 255) / 256, 256, 0, stream>>>(tp, dtp);
  // zero actg (h ring + g ring) + ctl + logits (contiguous)
  int nz = (int)(G * ACT_PER_GROUP / 2) + CT_WORDS + 128;
  zero_kernel<<<(nz + 255) / 256, 256, 0, stream>>>((unsigned int*)actg, nz);

  seq_kernel<<<dim3(NLAUNCH), dim3(512), 0, stream>>>(
      dtp, b1, cwv, vbv, bih, bhh, Wc, W1p, Whhp, Whh2p, Wihp, xfp,
      actg, ctl, logits);
  fin_kernel<<<dim3(1), dim3(128), 0, stream>>>(logits, bc, out);
}

// Round 6
// 1229.531 us; speedup vs baseline: 1.6281x; 1.6281x over previous
//
// ODE-RNN (B=128, F=512, I=128, H=512, O=1) on MI355X — Round 18.
// R17 (wave-specialization in 512-thr blocks) regressed 1559->2002us from 3
// implementation faults: (1) VGPR=116 => weight frags spilled to scratch
// (FETCH +6.6MB, WRITE +1.3MB, MfmaUtil down); (2) LDS mailbox stride 12 =>
// 8-way bank conflicts (1.57M); (3) cross-role LDS spin. R18 keeps the
// lockstep-split concept but specializes at BLOCK level: 8 cohorts claim
// 4 crit + 4 helper groups (256-thr blocks, launch_bounds(256,1) => 512-reg
// budget, no spill; no LDS mailbox; L2 flags only, R9 mechanics).
//   crit j:  poll{hflag>=f, mflag_j>=f} -> ld16 h_{f-1} + ld vpre(16B) ->
//            u=Whh*h (16 MFMA 4-deep) -> tanh -> publish h_f -> hflag=f+1;
//            deferred: accx=Wih*x_{f+1}, dsc=dt_{f+1}.
//   helper j: poll{hflag>=v+1, gflag>=v+1} -> ld16 h_v, ld16 g_{v-1} ->
//            z=W1*h_v -> publish g_v -> gflag=v+2 -> vpre=Whh2*g_{v-1} ->
//            mailbox slot (v+2)&3 -> mflag=v+2.
// Crit f uses vpre = Whh2*g1(h_{f-3}): staleness 2 (R15-proven accuracy).
// Ring safety: h-ring overwrite f gated by mflag>=f (helper f-2 done);
// g-ring by gflag>=v+1; mailbox by hflag_j>=v+1. Prologue: mailbox slot1 =
// vb = Whh2*relu(b1) (host precomp), g-ring slot3 = relu(b1), mbox zeroed.
// Predicted: 450-900us; MfmaUtil 6-10; VGPR ~290; LDS ~512B; conflicts 0.

#include <hip/hip_runtime.h>
#include <hip/hip_bf16.h>
#include <cstdint>
#include <cstddef>

#define HD 512
#define ID 128
#define FF 512
#define G 4          // groups (each owns 32 samples)
#define S 32         // samples per group
#define NBLK 16      // blocks per group role (32-col weight shards)
#define NLAUNCH 256  // blocks launched (>= 9 complete cohorts by pigeonhole)

// ctl word offsets (all zeroed before seq_kernel)
#define CT_TICKET 0          // [16] per-XCD ticket counters
#define CT_CLAIM 16          // group claim counter
#define CT_TOTAL 17          // registered-block counter
#define CT_MAP 20            // [256] cohort -> role+1 (0 = unclaimed)
#define CT_FSTRIDE 32        // words between flags (128B: own L2 line)
#define CT_PFLAG 512                                   // h flags [G][16*32]
#define CT_GFLAG (CT_PFLAG + G * NBLK * CT_FSTRIDE)    // g flags [G][16*32]
#define CT_MFLAG (CT_GFLAG + G * NBLK * CT_FSTRIDE)    // mbox flags [G][16*32]
#define CT_WORDS (CT_MFLAG + G * NBLK * CT_FSTRIDE)

#define XFRAG_ELEMS ((size_t)FF * 8 * 4 * 64 * 8)   // 8,388,608 bf16

// per-group activation region: [h ring 0..3][g ring 0..3] x S*512 bf16
#define ACT_PER_GROUP ((size_t)8 * S * 512)
// mailbox: [slot4][G][NBLK][wave4][lane64] float4
#define MBOX_F4 (4 * G * NBLK * 4 * 64)

typedef __bf16 bf16x8_t __attribute__((ext_vector_type(8)));
typedef unsigned short ushort8_t __attribute__((ext_vector_type(8)));
typedef unsigned short ushort4_t __attribute__((ext_vector_type(4)));
typedef float f32x4_t __attribute__((ext_vector_type(4)));

__device__ __forceinline__ unsigned short f2b(float x) {
  __hip_bfloat16 h = __float2bfloat16(x);
  return *reinterpret_cast<unsigned short*>(&h);
}
__device__ __forceinline__ bf16x8_t ld_frag(const unsigned short* p) {
  ushort8_t u = *reinterpret_cast<const ushort8_t*>(p);
  return __builtin_bit_cast(bf16x8_t, u);
}

// --- fp32 -> bf16 fragment-order weight pack (same layout as R3-R17) -------
__global__ void pack_kernel(const float* __restrict__ in,
                            unsigned short* __restrict__ out, int Kd) {
  int i = blockIdx.x * blockDim.x + threadIdx.x;
  int total = HD * Kd;
  if (i >= total) return;
  int KT = Kd >> 5;
  int j = i & 7;
  int lane = (i >> 3) & 63;
  int t = i >> 9;
  int kt = t % KT;
  int colt = t / KT;
  int n = lane & 15, kq = lane >> 4;
  out[i] = f2b(in[(size_t)(colt * 16 + n) * Kd + kt * 32 + kq * 8 + j]);
}

// --- C = A * B (512x512 fp32 row-major), naive-but-adequate (~tens of us) --
__global__ void mm512_kernel(const float* __restrict__ A,
                             const float* __restrict__ B,
                             float* __restrict__ C) {
  const int i = blockIdx.x;          // row
  const int j0 = threadIdx.x;        // col (and col+256)
  float acc0 = 0.f, acc1 = 0.f;
#pragma unroll 8
  for (int k = 0; k < 512; ++k) {
    float a = A[i * 512 + k];
    acc0 += a * B[k * 512 + j0];
    acc1 += a * B[k * 512 + j0 + 256];
  }
  C[i * 512 + j0] = acc0;
  C[i * 512 + j0 + 256] = acc1;
}

// --- out = W (512x512) * v (512) ------------------------------------------
__global__ void mv_kernel(const float* __restrict__ W,
                          const float* __restrict__ v,
                          float* __restrict__ out) {
  int i = blockIdx.x * blockDim.x + threadIdx.x;
  if (i >= 512) return;
  float s = 0.f;
#pragma unroll 8
  for (int k = 0; k < 512; ++k) s += W[(size_t)i * 512 + k] * v[k];
  out[i] = s;
}

// --- out = W (512x512) * relu(v) ------------------------------------------
__global__ void mv_relu_kernel(const float* __restrict__ W,
                               const float* __restrict__ v,
                               float* __restrict__ out) {
  int i = blockIdx.x * blockDim.x + threadIdx.x;
  if (i >= 512) return;
  float s = 0.f;
#pragma unroll 8
  for (int k = 0; k < 512; ++k) {
    float g = v[k] > 0.f ? v[k] : 0.f;
    s += W[(size_t)i * 512 + k] * g;
  }
  out[i] = s;
}

// --- x -> bf16 B-fragment order: xf[f][st=b>>4][kt<4][lane=n+16kq][8] ------
__global__ void xpack_kernel(const float* __restrict__ in,
                             unsigned short* __restrict__ out) {
  size_t i = (size_t)blockIdx.x * blockDim.x + threadIdx.x;
  if (i >= XFRAG_ELEMS) return;
  int e = (int)(i & 7);
  int lane = (int)((i >> 3) & 63);
  int kt = (int)((i >> 9) & 3);
  int st = (int)((i >> 11) & 7);
  int f = (int)(i >> 14);
  int n = lane & 15, kq = lane >> 4;
  int b = st * 16 + n;
  int ii = kt * 32 + kq * 8 + e;
  out[i] = f2b(in[((size_t)b * FF + f) * ID + ii]);
}

// --- dt table: dtp[f*128 + b] = tp[b][f] - tp[b][f-1] (0 at f=0) -----------
__global__ void dtpack_kernel(const float* __restrict__ tp,
                              float* __restrict__ dtp) {
  int i = blockIdx.x * blockDim.x + threadIdx.x;
  if (i >= FF * 128) return;
  int f = i >> 7, b = i & 127;
  dtp[i] = (f > 0) ? (tp[(size_t)b * FF + f] - tp[(size_t)b * FF + f - 1])
                   : 0.f;
}

__global__ void zero_kernel(unsigned int* __restrict__ p, int n) {
  int i = blockIdx.x * blockDim.x + threadIdx.x;
  if (i < n) p[i] = 0u;
}

// Load the 16 activation frags of this wave's K-slab into registers.
__device__ __forceinline__ void ld16(const ushort8_t* base, int row0,
                                     int lane, bf16x8_t a[16]) {
#pragma unroll
  for (int kt = 0; kt < 16; ++kt)
    a[kt] = __builtin_bit_cast(bf16x8_t, base[(row0 + kt) * 64 + lane]);
}
// acc += W-shard @ act, two interleaved 8-chains (helper-path version).
__device__ __forceinline__ f32x4_t mm16r(const bf16x8_t* wf,
                                         const bf16x8_t a[16], f32x4_t acc) {
  f32x4_t acc1 = {0.f, 0.f, 0.f, 0.f};
#pragma unroll
  for (int kt = 0; kt < 16; kt += 2) {
    acc  = __builtin_amdgcn_mfma_f32_16x16x32_bf16(wf[kt], a[kt], acc, 0, 0, 0);
    acc1 = __builtin_amdgcn_mfma_f32_16x16x32_bf16(wf[kt + 1], a[kt + 1], acc1,
                                                   0, 0, 0);
  }
  acc[0] += acc1[0]; acc[1] += acc1[1]; acc[2] += acc1[2]; acc[3] += acc1[3];
  return acc;
}
// Critical-path version: 4 interleaved chains x 4-deep (halved latency).
__device__ __forceinline__ f32x4_t mm16r44(const bf16x8_t* wf,
                                           const bf16x8_t a[16]) {
  f32x4_t c0 = {0.f, 0.f, 0.f, 0.f}, c1 = {0.f, 0.f, 0.f, 0.f};
  f32x4_t c2 = {0.f, 0.f, 0.f, 0.f}, c3 = {0.f, 0.f, 0.f, 0.f};
#pragma unroll
  for (int i = 0; i < 4; ++i) {
    c0 = __builtin_amdgcn_mfma_f32_16x16x32_bf16(wf[i * 4 + 0], a[i * 4 + 0],
                                                 c0, 0, 0, 0);
    c1 = __builtin_amdgcn_mfma_f32_16x16x32_bf16(wf[i * 4 + 1], a[i * 4 + 1],
                                                 c1, 0, 0, 0);
    c2 = __builtin_amdgcn_mfma_f32_16x16x32_bf16(wf[i * 4 + 2], a[i * 4 + 2],
                                                 c2, 0, 0, 0);
    c3 = __builtin_amdgcn_mfma_f32_16x16x32_bf16(wf[i * 4 + 3], a[i * 4 + 3],
                                                 c3, 0, 0, 0);
  }
#pragma unroll
  for (int r_ = 0; r_ < 4; ++r_) c0[r_] = (c0[r_] + c1[r_]) + (c2[r_] + c3[r_]);
  return c0;
}
// fast tanh: clamp + __expf + rcp, |err| ~ 1e-6, no libm call.
__device__ __forceinline__ float ftanh(float x) {
  float xc = fminf(fmaxf(x, -15.f), 15.f);
  float e = __expf(2.f * xc);
  return (e - 1.f) * __builtin_amdgcn_rcpf(e + 1.f);
}

// --- the sequential recurrence ---------------------------------------------
__global__ __launch_bounds__(256, 1) void seq_kernel(
    const float* __restrict__ dtp,
    const float* __restrict__ b1, const float* __restrict__ cw,
    const float* __restrict__ vb,
    const float* __restrict__ bih, const float* __restrict__ bhh,
    const float* __restrict__ Wc,
    const unsigned short* __restrict__ W1p,
    const unsigned short* __restrict__ Whhp,
    const unsigned short* __restrict__ Whh2p,
    const unsigned short* __restrict__ Wihp,
    const unsigned short* __restrict__ xf,
    unsigned short* __restrict__ actg,   // G * ACT_PER_GROUP bf16
    float* __restrict__ mbox,            // MBOX_F4 float4 (as float*)
    unsigned int* __restrict__ ctl,      // control words (see CT_*)
    float* __restrict__ logits) {        // 128 fp32, pre-zeroed
  __shared__ float redl[S][2];
  __shared__ int role[2];

  const int tid = threadIdx.x;

  // ---- XCD-aware registration & role claiming (tid 0; R5-R17 proven) ------
  if (tid == 0) {
    unsigned xcc;
    asm volatile("s_getreg_b32 %0, hwreg(HW_REG_XCC_ID, 0, 32)" : "=s"(xcc));
    const int xcd = (int)(xcc & 15u);
    unsigned rank = __hip_atomic_fetch_add(&ctl[CT_TICKET + xcd], 1u,
                                           __ATOMIC_RELAXED,
                                           __HIP_MEMORY_SCOPE_AGENT);
    const unsigned slot = (unsigned)xcd * 16u + (rank >> 4);
    if ((rank & 15u) == 15u) {  // cohort completer claims a role id
      unsigned gg = __hip_atomic_fetch_add(&ctl[CT_CLAIM], 1u,
                                           __ATOMIC_RELAXED,
                                           __HIP_MEMORY_SCOPE_AGENT);
      __hip_atomic_store(&ctl[CT_MAP + slot], gg + 1u, __ATOMIC_RELAXED,
                         __HIP_MEMORY_SCOPE_AGENT);
      asm volatile("s_waitcnt vmcnt(0)" ::: "memory");  // publish before total
    }
    __hip_atomic_fetch_add(&ctl[CT_TOTAL], 1u, __ATOMIC_RELAXED,
                           __HIP_MEMORY_SCOPE_AGENT);
    unsigned m;
    for (;;) {
      m = __hip_atomic_load(&ctl[CT_MAP + slot], __ATOMIC_RELAXED,
                            __HIP_MEMORY_SCOPE_AGENT);
      if (m) break;
      if (__hip_atomic_load(&ctl[CT_TOTAL], __ATOMIC_RELAXED,
                            __HIP_MEMORY_SCOPE_AGENT) >= (unsigned)NLAUNCH) {
        m = __hip_atomic_load(&ctl[CT_MAP + slot], __ATOMIC_RELAXED,
                              __HIP_MEMORY_SCOPE_AGENT);
        break;
      }
      __builtin_amdgcn_s_sleep(2);
    }
    role[0] = (m == 0 || m > (unsigned)(2 * G)) ? -1 : (int)(m - 1);
    role[1] = (int)(rank & 15u);
  }
  __syncthreads();
  if (role[0] < 0) return;       // surplus / incomplete cohort: exit
  const int rid = role[0];       // 0..3 crit group, 4..7 helper group
  const int g = rid & 3;
  const bool helper = rid >= G;
  const int j = role[1];         // 32-col weight shard 0..15

  const int wave = tid >> 6;     // 0..3
  const int lane = tid & 63;
  const int n = lane & 15;
  const int kq = lane >> 4;
  const int ct = wave & 1;         // col-tile within shard
  const int rt = wave >> 1;        // row-tile (samples)
  const int colt = j * 2 + ct;     // global 16-col tile
  const int sl2 = rt * 16 + n;     // this lane's sample
  const int gc0 = j * 32 + ct * 16 + kq * 4;  // lane's 4-col base
  const int s0 = g * S;

  unsigned short* const myact = actg + (size_t)g * ACT_PER_GROUP;
  unsigned int* const hf = &ctl[CT_PFLAG + g * NBLK * CT_FSTRIDE];
  unsigned int* const gf = &ctl[CT_GFLAG + g * NBLK * CT_FSTRIDE];
  unsigned int* const mf = &ctl[CT_MFLAG + g * NBLK * CT_FSTRIDE];
  // mailbox lane address (float4 index)
  auto mbx = [&](int slot) {
    return mbox + (size_t)((((slot * G + g) * NBLK + j) * 4 + wave) * 64 +
                           lane) * 4;
  };

  // Producer store offset (elems) in consumer B-frag order (R9-proven).
  const size_t soff =
      ((size_t)(rt * 16 + j) * 64 + n + 16 * (2 * ct + (kq >> 1))) * 8 +
      (kq & 1) * 4;
  const int row0 = rt * 16;

  asm volatile("buffer_inv" ::: "memory");   // drop any pre-kernel L1 lines
  asm volatile("s_waitcnt vmcnt(0)" ::: "memory");

  if (!helper) {
    // ================= CRITICAL blocks: the gating chain =================
    bf16x8_t whhf[16], wihf[4];
#pragma unroll
    for (int kt = 0; kt < 16; ++kt)
      whhf[kt] = ld_frag(Whhp + (size_t)(colt * 16 + kt) * 512 + lane * 8);
#pragma unroll
    for (int kt = 0; kt < 4; ++kt)
      wihf[kt] = ld_frag(Wihp + (size_t)(colt * 4 + kt) * 512 + lane * 8);
    const f32x4_t cwv4 = *reinterpret_cast<const f32x4_t*>(&cw[gc0]);
    f32x4_t bbv;
#pragma unroll
    for (int r_ = 0; r_ < 4; ++r_) bbv[r_] = bih[gc0 + r_] + bhh[gc0 + r_];
    f32x4_t fsv = {0.f, 0.f, 0.f, 0.f};

    // poll: lanes 0-15 hflag_i >= f; lane 16: mflag_j >= f; rest pass.
    auto poll_c = [&](unsigned wf_) {
      volatile const unsigned* fb = (volatile const unsigned*)hf;
      int fi = lane & 15;
      unsigned want = wf_;
      if (lane == 16) { fb = (volatile const unsigned*)mf; fi = j; }
      else if (lane > 16 && lane < 32) want = 0u;
      for (;;) {
        asm volatile("buffer_inv" ::: "memory");
        unsigned vv = fb[fi * CT_FSTRIDE];
        if (__ballot(vv < want) == 0ull) break;
      }
    };

    // prologue: accx = Wih*x_0, dsc = dt_0 (= 0)
    f32x4_t accx = {0.f, 0.f, 0.f, 0.f};
    {
      const ushort8_t* xsrc =
          (const ushort8_t*)xf + (size_t)((0 * 8 + g * 2 + rt) * 4) * 64;
#pragma unroll
      for (int kt = 0; kt < 4; ++kt) {
        bf16x8_t a = __builtin_bit_cast(bf16x8_t, xsrc[kt * 64 + lane]);
        accx = __builtin_amdgcn_mfma_f32_16x16x32_bf16(wihf[kt], a, accx,
                                                       0, 0, 0);
      }
    }
    float dsc = 0.f;

#pragma unroll 1
    for (int f = 0; f < FF; ++f) {
      poll_c((unsigned)f);
      // vpre from mailbox slot f&3 (16B) + h_{f-1} gather
      const f32x4_t vpre = *reinterpret_cast<const f32x4_t*>(mbx(f & 3));
      bf16x8_t ah[16];
      ld16((const ushort8_t*)(myact + (size_t)((f + 3) & 3) * (S * 512)),
           row0, lane, ah);
      f32x4_t u = mm16r44(whhf, ah);
      unsigned short* dsth = myact + (size_t)(f & 3) * (S * 512);
      ushort4_t oh;
#pragma unroll
      for (int r_ = 0; r_ < 4; ++r_) {
        float pre = accx[r_] + u[r_] + dsc * (vpre[r_] + cwv4[r_]) + bbv[r_];
        float t = ftanh(pre);
        fsv[r_] += t;
        oh[r_] = f2b(t);
      }
      *reinterpret_cast<ushort4_t*>(dsth + soff) = oh;
      asm volatile("s_waitcnt vmcnt(0)" ::: "memory");
      __syncthreads();
      if (tid == 0)
        *(volatile unsigned int*)(hf + j * CT_FSTRIDE) = (unsigned)(f + 1);
      // deferred (hidden under next poll): accx = Wih*x_{f+1}, dsc=dt_{f+1}
      accx = (f32x4_t){0.f, 0.f, 0.f, 0.f};
      if (f + 1 < FF) {
        dsc = dtp[(f + 1) * 128 + s0 + sl2];
        const ushort8_t* xsrc =
            (const ushort8_t*)xf +
            (size_t)(((f + 1) * 8 + g * 2 + rt) * 4) * 64;
#pragma unroll
        for (int kt = 0; kt < 4; ++kt) {
          bf16x8_t ax = __builtin_bit_cast(bf16x8_t, xsrc[kt * 64 + lane]);
          accx = __builtin_amdgcn_mfma_f32_16x16x32_bf16(wihf[kt], ax, accx,
                                                         0, 0, 0);
        }
      }
    }

    // ---- classifier partial (crit blocks only) ----
    {
      float p = fsv[0] * Wc[gc0] + fsv[1] * Wc[gc0 + 1] +
                fsv[2] * Wc[gc0 + 2] + fsv[3] * Wc[gc0 + 3];
      p += __shfl_xor(p, 16, 64);
      p += __shfl_xor(p, 32, 64);
      if (lane < 16) redl[rt * 16 + lane][ct] = p;
    }
    __syncthreads();
    if (tid < S) {
      float v = redl[tid][0] + redl[tid][1];
      atomicAdd(&logits[s0 + tid], v);   // device-scope, cross-XCD safe
    }
  } else {
    // ================= HELPER blocks: g + vpre pipeline ==================
    bf16x8_t w1f[16], whh2f[16];
#pragma unroll
    for (int kt = 0; kt < 16; ++kt) {
      w1f[kt]   = ld_frag(W1p   + (size_t)(colt * 16 + kt) * 512 + lane * 8);
      whh2f[kt] = ld_frag(Whh2p + (size_t)(colt * 16 + kt) * 512 + lane * 8);
    }
    const f32x4_t b1v = *reinterpret_cast<const f32x4_t*>(&b1[gc0]);

    // poll: lanes 0-15 hflag_i >= wh; lanes 16-31 gflag_i >= wg; rest pass.
    auto poll_h = [&](unsigned wh, unsigned wg) {
      const bool gl = (lane >= 16 && lane < 32);
      volatile const unsigned* fb =
          gl ? (volatile const unsigned*)gf : (volatile const unsigned*)hf;
      const int fi = lane & 15;
      const unsigned want = (lane < 32) ? (gl ? wg : wh) : 0u;
      for (;;) {
        asm volatile("buffer_inv" ::: "memory");
        unsigned vv = fb[fi * CT_FSTRIDE];
        if (__ballot(vv < want) == 0ull) break;
      }
    };

    // ---- prologue: g_{-1} = relu(b1) -> ring slot 3; mailbox slot 1 = vb;
    //      (mailbox slot 0 is pre-zeroed; dsc_0 = 0 makes it inert) ----
    {
      ushort4_t og;
#pragma unroll
      for (int r_ = 0; r_ < 4; ++r_)
        og[r_] = f2b(b1v[r_] > 0.f ? b1v[r_] : 0.f);
      *reinterpret_cast<ushort4_t*>(
          myact + (size_t)(4 + 3) * (S * 512) + soff) = og;
      f32x4_t v1;
#pragma unroll
      for (int r_ = 0; r_ < 4; ++r_) v1[r_] = vb[gc0 + r_];
      *reinterpret_cast<f32x4_t*>(mbx(1)) = v1;
      asm volatile("s_waitcnt vmcnt(0)" ::: "memory");
      __syncthreads();
      if (tid == 0) {
        *(volatile unsigned int*)(gf + j * CT_FSTRIDE) = 1u;
        *(volatile unsigned int*)(mf + j * CT_FSTRIDE) = 1u;
      }
    }

#pragma unroll 1
    for (int v = 0; v <= FF - 3; ++v) {
      poll_h((unsigned)(v + 1), (unsigned)(v + 1));
      bf16x8_t ah[16], ag[16];
      ld16((const ushort8_t*)(myact + (size_t)(v & 3) * (S * 512)),
           row0, lane, ah);                       // h_v
      ld16((const ushort8_t*)(myact + (size_t)(4 + ((v + 3) & 3)) * (S * 512)),
           row0, lane, ag);                       // g_{v-1}
      // z = W1 * h_v -> publish g_v (early flag)
      f32x4_t z = {0.f, 0.f, 0.f, 0.f};
      z = mm16r(w1f, ah, z);
      ushort4_t og;
#pragma unroll
      for (int r_ = 0; r_ < 4; ++r_) {
        float zz = z[r_] + b1v[r_];
        og[r_] = f2b(zz > 0.f ? zz : 0.f);
      }
      *reinterpret_cast<ushort4_t*>(
          myact + (size_t)(4 + (v & 3)) * (S * 512) + soff) = og;
      asm volatile("s_waitcnt vmcnt(0)" ::: "memory");
      __syncthreads();
      if (tid == 0)
        *(volatile unsigned int*)(gf + j * CT_FSTRIDE) = (unsigned)(v + 2);
      // vpre = Whh2 * g_{v-1} -> mailbox slot (v+2)&3 for crit frame v+2
      f32x4_t vp = {0.f, 0.f, 0.f, 0.f};
      vp = mm16r(whh2f, ag, vp);
      *reinterpret_cast<f32x4_t*>(mbx((v + 2) & 3)) = vp;
      asm volatile("s_waitcnt vmcnt(0)" ::: "memory");
      __syncthreads();
      if (tid == 0)
        *(volatile unsigned int*)(mf + j * CT_FSTRIDE) = (unsigned)(v + 2);
    }
  }
}

__global__ void fin_kernel(const float* __restrict__ logits,
                           const float* __restrict__ bc,
                           float* __restrict__ out) {
  int b = threadIdx.x;
  if (b < 128) out[b] = 1.f / (1.f + __expf(-(logits[b] * (1.f / FF) + bc[0])));
}

// --- launch -----------------------------------------------------------------
extern "C" void kernel_launch(void* const* d_in, const int* in_sizes, int n_in,
                              void* d_out, int out_size, void* d_ws, size_t ws_size,
                              hipStream_t stream) {
  const float* x   = (const float*)d_in[0];
  const float* tp  = (const float*)d_in[1];
  const float* W1  = (const float*)d_in[2];
  const float* b1  = (const float*)d_in[3];
  const float* W2  = (const float*)d_in[4];
  const float* b2  = (const float*)d_in[5];
  const float* Wih = (const float*)d_in[6];
  const float* Whh = (const float*)d_in[7];
  const float* bih = (const float*)d_in[8];
  const float* bhh = (const float*)d_in[9];
  const float* Wc  = (const float*)d_in[10];
  const float* bc  = (const float*)d_in[11];
  float* out = (float*)d_out;

  unsigned short* W1p   = (unsigned short*)d_ws;
  unsigned short* Whhp  = W1p + (size_t)HD * HD;
  unsigned short* Whh2p = Whhp + (size_t)HD * HD;
  unsigned short* Wihp  = Whh2p + (size_t)HD * HD;
  unsigned short* xfp   = Wihp + (size_t)HD * ID;
  float*          dtp   = (float*)(xfp + XFRAG_ELEMS);
  float*          cwv   = dtp + FF * 128;
  float*          vbv   = cwv + HD;
  float*          Whh2t = vbv + HD;                 // fp32 temp 1MB
  unsigned short* actg  = (unsigned short*)(Whh2t + (size_t)HD * HD);
  float*          mbox  = (float*)(actg + (size_t)G * ACT_PER_GROUP);
  unsigned int*   ctl   = (unsigned int*)(mbox + (size_t)MBOX_F4 * 4);
  float*          logits = (float*)(ctl + CT_WORDS);
  // total ws use ~22 MB

  // precompute Whh2 = Whh*W2, cw = Whh*b2, vb = Whh2*relu(b1)
  mm512_kernel<<<512, 256, 0, stream>>>(Whh, W2, Whh2t);
  mv_kernel<<<2, 256, 0, stream>>>(Whh, b2, cwv);
  mv_relu_kernel<<<2, 256, 0, stream>>>(Whh2t, b1, vbv);

  pack_kernel<<<(HD * HD + 255) / 256, 256, 0, stream>>>(W1, W1p, HD);
  pack_kernel<<<(HD * HD + 255) / 256, 256, 0, stream>>>(Whh, Whhp, HD);
  pack_kernel<<<(HD * HD + 255) / 256, 256, 0, stream>>>(Whh2t, Whh2p, HD);
  pack_kernel<<<(HD * ID + 255) / 256, 256, 0, stream>>>(Wih, Wihp, ID);
  xpack_kernel<<<(int)((XFRAG_ELEMS + 255) / 256), 256, 0, stream>>>(x, xfp);
  dtpack_kernel<<<(FF * 128 + 255) / 256, 256, 0, stream>>>(tp, dtp);
  // zero actg + mbox + ctl + logits (contiguous)
  int nz = (int)(G * ACT_PER_GROUP / 2) + MBOX_F4 * 4 + CT_WORDS + 128;
  zero_kernel<<<(nz + 255) / 256, 256, 0, stream>>>((unsigned int*)actg, nz);

  seq_kernel<<<dim3(NLAUNCH), dim3(256), 0, stream>>>(
      dtp, b1, cwv, vbv, bih, bhh, Wc, W1p, Whhp, Whh2p, Wihp, xfp,
      actg, mbox, ctl, logits);
  fin_kernel<<<dim3(1), dim3(128), 0, stream>>>(logits, bc, out);
}